// Round 2
// baseline (1193.776 us; speedup 1.0000x reference)
//
#include <hip/hip_runtime.h>

typedef __bf16 bf16x8 __attribute__((ext_vector_type(8)));
typedef float f32x4 __attribute__((ext_vector_type(4)));

#define WT_SLOT 65536              // elements per 256x256 bf16 weight slot
#define WS_GKEYS 0                 // 512 u32 (tb keys, br keys)
#define WS_VEC0  4096              // 256 f32
#define WS_COUNTS 8192             // 256 u32
#define WS_BASES 12288             // 256 u32
#define WS_IDX   16384             // 4096 i32
#define WS_WT    32768             // 11 slots * 131072 B

__device__ __forceinline__ float fast_tanh(float x) {
  float e = __builtin_amdgcn_exp2f(x * 2.8853900817779268f); // exp(2x)
  return 1.0f - 2.0f * __builtin_amdgcn_rcpf(e + 1.0f);
}
__device__ __forceinline__ unsigned fkey(float f) {
  unsigned u = __float_as_uint(f);
  return (u & 0x80000000u) ? ~u : (u | 0x80000000u);
}
__device__ __forceinline__ float unfkey(unsigned k) {
  unsigned u = (k & 0x80000000u) ? (k & 0x7FFFFFFFu) : ~k;
  return __uint_as_float(u);
}
// swizzled LDS byte offset for a [128][256] bf16 tile, row stride 512B
__device__ __forceinline__ int lds_off(int r, int cb) {
  return r * 512 + (cb ^ ((r & 7) << 4));
}

// ---- 128x256 @ 256x256 GEMM step: A from LDS (swizzled), B from global (bf16 [N][K]) ----
__device__ __forceinline__ void gemm_step(char* lds, const __bf16* wt, int lane,
                                          int m0, f32x4 acc[2][16]) {
  const int rlo = lane & 15;
  const int khi = (lane >> 4) << 3;
#pragma unroll
  for (int k0 = 0; k0 < 256; k0 += 32) {
    int kk = k0 + khi;
    bf16x8 a0 = *(const bf16x8*)(lds + lds_off(m0 + rlo, 2 * kk));
    bf16x8 a1 = *(const bf16x8*)(lds + lds_off(m0 + 16 + rlo, 2 * kk));
#pragma unroll
    for (int nt = 0; nt < 16; ++nt) {
      bf16x8 b = *(const bf16x8*)(wt + (nt * 16 + rlo) * 256 + kk);
      acc[0][nt] = __builtin_amdgcn_mfma_f32_16x16x32_bf16(a0, b, acc[0][nt], 0, 0, 0);
      acc[1][nt] = __builtin_amdgcn_mfma_f32_16x16x32_bf16(a1, b, acc[1][nt], 0, 0, 0);
    }
  }
}

template <bool TANH, bool WRITE, bool CMAX>
__device__ __forceinline__ void epilogue(char* lds, const float* bias, int lane,
                                         int m0, f32x4 acc[2][16], float* mbuf, int wave) {
  const int rlo = lane & 15;
  const int rhi = (lane >> 4) << 2;
#pragma unroll
  for (int nt = 0; nt < 16; ++nt) {
    int c = nt * 16 + rlo;
    float bv = bias[c];
    float cm = -3.4e38f;
#pragma unroll
    for (int mt = 0; mt < 2; ++mt) {
#pragma unroll
      for (int rg = 0; rg < 4; ++rg) {
        float v = acc[mt][nt][rg] + bv;
        if (TANH) v = fast_tanh(v);
        if (WRITE) {
          int r = m0 + mt * 16 + rhi + rg;
          *(__bf16*)(lds + lds_off(r, 2 * c)) = (__bf16)v;
        }
        if (CMAX) cm = fmaxf(cm, v);
      }
    }
    if (CMAX) {
      cm = fmaxf(cm, __shfl_xor(cm, 16, 64));
      cm = fmaxf(cm, __shfl_xor(cm, 32, 64));
      if (lane < 16) mbuf[wave * 256 + c] = cm;
    }
  }
}

template <bool TANH, bool WRITE, bool CMAX>
__device__ __forceinline__ void layer256(char* lds, const __bf16* wt, const float* bias,
                                         int lane, int wave, float* mbuf) {
  f32x4 acc[2][16];
#pragma unroll
  for (int mt = 0; mt < 2; ++mt)
#pragma unroll
    for (int nt = 0; nt < 16; ++nt) acc[mt][nt] = (f32x4){0.f, 0.f, 0.f, 0.f};
  gemm_step(lds, wt, lane, wave << 5, acc);
  __syncthreads();
  epilogue<TANH, WRITE, CMAX>(lds, bias, lane, wave << 5, acc, mbuf, wave);
  __syncthreads();
}

// ------------------ weight convert/transpose to bf16 + key init ------------------
struct ConvArgs { const float* src[11]; };
__global__ void K_conv(ConvArgs a, __bf16* wt, unsigned* gkeys) {
  int job = blockIdx.x;
  int t = threadIdx.x;
  if (job == 11) {
    if (blockIdx.y == 0) { gkeys[t] = 0u; gkeys[256 + t] = 0u; }
    return;
  }
  const float* s = a.src[job];
  __bf16* d = wt + (size_t)job * WT_SLOT;
#pragma unroll
  for (int it = 0; it < 16; ++it) {
    int i = blockIdx.y * 4096 + it * 256 + t;  // dst linear index, [N=256][K=256]
    int n = i >> 8, k = i & 255;
    d[i] = (__bf16)s[(k << 8) | n];            // src is [K][N] fp32 (first 256 rows)
  }
}

// ------------------ big fused MLP (tb & br) + column max ------------------
struct BigArgs {
  const float* x;
  const __bf16* wt;
  const float* w0[2]; const float* b0[2];
  const float* b1[2]; const float* b2[2]; const float* b3[2];
  unsigned* gkeys;
};
__global__ __launch_bounds__(256, 2) void K_big(BigArgs a) {
  __shared__ char lds[65536];
  int tid = threadIdx.x, lane = tid & 63, wave = tid >> 6;
  int mlp = blockIdx.x >> 11;
  int row0 = (blockIdx.x & 2047) << 7;
  {  // layer0: 3 -> 256, VALU (thread t owns column t)
    const float* W0 = a.w0[mlp];
    float wa = W0[tid], wb = W0[256 + tid], wc = W0[512 + tid], bb = a.b0[mlp][tid];
    const float* xr = a.x + (size_t)row0 * 3;
#pragma unroll 4
    for (int r = 0; r < 128; ++r) {
      float v = fmaf(xr[r * 3 + 2], wc, fmaf(xr[r * 3 + 1], wb, fmaf(xr[r * 3], wa, bb)));
      *(__bf16*)(lds + lds_off(r, 2 * tid)) = (__bf16)fast_tanh(v);
    }
  }
  __syncthreads();
  const __bf16* wt = a.wt + (size_t)(mlp * 3) * WT_SLOT;
  float* mbuf = (float*)lds;
  layer256<true, true, false>(lds, wt, a.b1[mlp], lane, wave, nullptr);
  layer256<true, true, false>(lds, wt + WT_SLOT, a.b2[mlp], lane, wave, nullptr);
  layer256<false, false, true>(lds, wt + 2 * WT_SLOT, a.b3[mlp], lane, wave, mbuf);
  // cross-wave max + global atomic on ordered keys (max = commutative -> deterministic)
  float m = fmaxf(fmaxf(mbuf[tid], mbuf[256 + tid]), fmaxf(mbuf[512 + tid], mbuf[768 + tid]));
  atomicMax(a.gkeys + mlp * 256 + tid, fkey(m));
}

// ------------------ patch membership / ordered compaction ------------------
__device__ __forceinline__ bool in_patch(const float* x, int r) {
  float a = x[r * 3], b = x[r * 3 + 1], c = x[r * 3 + 2];
  int c0 = min(max((int)floorf(a * 10.0f), 0), 9);
  int c1 = min(max((int)floorf(b * 10.0f), 0), 9);
  int c2 = min(max((int)floorf(c * 10.0f), 0), 9);
  return (c0 == 9) && (c1 == 9) && (c2 == 5);  // patch id 995
}
__global__ void K_count(const float* x, unsigned* counts) {
  __shared__ unsigned sw[4];
  int b = blockIdx.x, t = threadIdx.x;
  int base = b * 1024 + t * 4;
  unsigned c = 0;
#pragma unroll
  for (int j = 0; j < 4; ++j) c += in_patch(x, base + j) ? 1u : 0u;
#pragma unroll
  for (int o = 1; o < 64; o <<= 1) c += __shfl_xor((int)c, o, 64);
  if ((t & 63) == 0) sw[t >> 6] = c;
  __syncthreads();
  if (t == 0) counts[b] = sw[0] + sw[1] + sw[2] + sw[3];
}
__global__ void K_scan(const unsigned* counts, unsigned* bases) {
  __shared__ unsigned s[256];
  int t = threadIdx.x;
  unsigned c = counts[t];
  s[t] = c; __syncthreads();
  for (int o = 1; o < 256; o <<= 1) {
    unsigned v = (t >= o) ? s[t - o] : 0u;
    __syncthreads();
    s[t] += v;
    __syncthreads();
  }
  bases[t] = s[t] - c;
}
__global__ void K_fill(const float* x, const unsigned* bases, int* idx) {
  __shared__ unsigned s[256];
  int b = blockIdx.x, t = threadIdx.x;
  int base = b * 1024 + t * 4;
  unsigned fm = 0, c = 0;
#pragma unroll
  for (int j = 0; j < 4; ++j) {
    bool f = in_patch(x, base + j);
    fm |= (f ? 1u : 0u) << j;
    c += f ? 1u : 0u;
  }
  s[t] = c; __syncthreads();
  for (int o = 1; o < 256; o <<= 1) {
    unsigned v = (t >= o) ? s[t - o] : 0u;
    __syncthreads();
    s[t] += v;
    __syncthreads();
  }
  unsigned pos = bases[b] + s[t] - c;
#pragma unroll
  for (int j = 0; j < 4; ++j)
    if (fm & (1u << j)) idx[pos++] = base + j;
}

// ------------------ finalize params + broadcast part of o-layer1 ------------------
__global__ void K_vec(const unsigned* gkeys, const float* ow0, const float* ob0, float* vec0) {
  __shared__ float gp[256], lp[256];
  int t = threadIdx.x;
  gp[t] = unfkey(gkeys[t]);        // tb -> global_param
  lp[t] = unfkey(gkeys[256 + t]);  // br -> local_param
  __syncthreads();
  float acc = ob0[t];
  for (int k = 0; k < 256; ++k) {
    acc = fmaf(lp[k], ow0[(256 + k) * 256 + t], acc);
    acc = fmaf(gp[k], ow0[(512 + k) * 256 + t], acc);
  }
  vec0[t] = acc;
}

// ------------------ patch pipeline: tr-MLP + out-MLP + gt copy ------------------
struct SmallArgs {
  const float* x; const float* y; const int* idx; int MM;
  const __bf16* wt;
  const float* trw0; const float* trb0;
  const float* trb1; const float* trb2; const float* trb3;
  const float* vec0; const float* ob1; const float* ow2; const float* ob2;
  float* out;
};
__global__ __launch_bounds__(256, 2) void K_small(SmallArgs a) {
  __shared__ char lds[65536];
  int tid = threadIdx.x, lane = tid & 63, wave = tid >> 6;
  int pr0 = blockIdx.x << 7;
  {  // gather x_patch, write gt (fp32 exact), layer0 of tr (thread pair (r,half) owns row r)
    int r = tid >> 1, half = tid & 1;
    int pr = pr0 + r;
    int j = a.idx[min(pr, a.MM - 1)];
    if (half == 0 && pr < a.MM) a.out[a.MM + pr] = a.y[j];
    float x0 = a.x[j * 3], x1 = a.x[j * 3 + 1], x2 = a.x[j * 3 + 2];
    for (int i = 0; i < 128; ++i) {
      int c = (half << 7) + i;
      float v = fmaf(x2, a.trw0[512 + c], fmaf(x1, a.trw0[256 + c], fmaf(x0, a.trw0[c], a.trb0[c])));
      *(__bf16*)(lds + lds_off(r, 2 * c)) = (__bf16)fast_tanh(v);
    }
  }
  __syncthreads();
  const __bf16* wt_tr = a.wt + (size_t)6 * WT_SLOT;
  layer256<true, true, false>(lds, wt_tr, a.trb1, lane, wave, nullptr);
  layer256<true, true, false>(lds, wt_tr + WT_SLOT, a.trb2, lane, wave, nullptr);
  layer256<false, true, false>(lds, wt_tr + 2 * WT_SLOT, a.trb3, lane, wave, nullptr);  // local_coord
  layer256<true, true, false>(lds, a.wt + (size_t)9 * WT_SLOT, a.vec0, lane, wave, nullptr);  // o1
  layer256<true, true, false>(lds, a.wt + (size_t)10 * WT_SLOT, a.ob1, lane, wave, nullptr);  // o2
  {  // o3: 256 -> 1 dot per row, fp32 out
    int r = tid >> 1, half = tid & 1, pr = pr0 + r;
    float s = 0.f;
    for (int i = 0; i < 128; ++i) {
      int c = (half << 7) + i;
      s = fmaf((float)*(const __bf16*)(lds + lds_off(r, 2 * c)), a.ow2[c], s);
    }
    s += __shfl_xor(s, 1, 64);
    if (half == 0 && pr < a.MM) a.out[pr] = s + a.ob2[0];
  }
}

extern "C" void kernel_launch(void* const* d_in, const int* in_sizes, int n_in,
                              void* d_out, int out_size, void* d_ws, size_t ws_size,
                              hipStream_t stream) {
  const float* x = (const float*)d_in[0];
  const float* y = (const float*)d_in[1];
  char* ws = (char*)d_ws;
  unsigned* gkeys = (unsigned*)(ws + WS_GKEYS);
  float* vec0 = (float*)(ws + WS_VEC0);
  unsigned* counts = (unsigned*)(ws + WS_COUNTS);
  unsigned* bases = (unsigned*)(ws + WS_BASES);
  int* idx = (int*)(ws + WS_IDX);
  __bf16* wt = (__bf16*)(ws + WS_WT);
  int MM = out_size / 2;

  ConvArgs ca;
  for (int m = 0; m < 3; ++m)           // 0=tb,1=br,2=tr ; L -> w_{L+1}
    for (int L = 0; L < 3; ++L)
      ca.src[m * 3 + L] = (const float*)d_in[2 + m * 8 + 2 * (L + 1)];
  ca.src[9] = (const float*)d_in[26];   // o_w0 (top 256 rows used)
  ca.src[10] = (const float*)d_in[28];  // o_w1
  hipLaunchKernelGGL(K_conv, dim3(12, 16), dim3(256), 0, stream, ca, wt, gkeys);

  K_count<<<256, 256, 0, stream>>>(x, counts);
  K_scan<<<1, 256, 0, stream>>>(counts, bases);
  K_fill<<<256, 256, 0, stream>>>(x, bases, idx);

  BigArgs ba;
  ba.x = x; ba.wt = wt; ba.gkeys = gkeys;
  ba.w0[0] = (const float*)d_in[2];  ba.b0[0] = (const float*)d_in[3];
  ba.b1[0] = (const float*)d_in[5];  ba.b2[0] = (const float*)d_in[7];  ba.b3[0] = (const float*)d_in[9];
  ba.w0[1] = (const float*)d_in[10]; ba.b0[1] = (const float*)d_in[11];
  ba.b1[1] = (const float*)d_in[13]; ba.b2[1] = (const float*)d_in[15]; ba.b3[1] = (const float*)d_in[17];
  K_big<<<4096, 256, 0, stream>>>(ba);

  K_vec<<<1, 256, 0, stream>>>(gkeys, (const float*)d_in[26], (const float*)d_in[27], vec0);

  if (MM > 0) {
    SmallArgs sa;
    sa.x = x; sa.y = y; sa.idx = idx; sa.MM = MM; sa.wt = wt;
    sa.trw0 = (const float*)d_in[18]; sa.trb0 = (const float*)d_in[19];
    sa.trb1 = (const float*)d_in[21]; sa.trb2 = (const float*)d_in[23]; sa.trb3 = (const float*)d_in[25];
    sa.vec0 = vec0;
    sa.ob1 = (const float*)d_in[29];
    sa.ow2 = (const float*)d_in[30]; sa.ob2 = (const float*)d_in[31];
    sa.out = (float*)d_out;
    K_small<<<(MM + 127) / 128, 256, 0, stream>>>(sa);
  }
}

// Round 3
// 853.724 us; speedup vs baseline: 1.3983x; 1.3983x over previous
//
#include <hip/hip_runtime.h>

typedef __bf16 bf16x8 __attribute__((ext_vector_type(8)));
typedef float f32x4 __attribute__((ext_vector_type(4)));

#define WT_SLOT 65536              // elements per 256x256 bf16 weight slot (packed fragment order)
#define WS_GKEYS 0                 // 512 u32 (tb keys, br keys)
#define WS_VEC0  4096              // 256 f32
#define WS_COUNTS 8192             // 256 u32
#define WS_BASES 12288             // 256 u32
#define WS_IDX   16384             // 4096 i32
#define WS_WT    32768             // 11 slots * 131072 B

__device__ __forceinline__ float fast_tanh(float x) {
  float e = __builtin_amdgcn_exp2f(x * 2.8853900817779268f); // exp(2x)
  return 1.0f - 2.0f * __builtin_amdgcn_rcpf(e + 1.0f);
}
__device__ __forceinline__ unsigned fkey(float f) {
  unsigned u = __float_as_uint(f);
  return (u & 0x80000000u) ? ~u : (u | 0x80000000u);
}
__device__ __forceinline__ float unfkey(unsigned k) {
  unsigned u = (k & 0x80000000u) ? (k & 0x7FFFFFFFu) : ~k;
  return __uint_as_float(u);
}
// swizzled LDS byte offset for a [128][256] bf16 tile, row stride 512B
__device__ __forceinline__ int lds_off(int r, int cb) {
  return r * 512 + (cb ^ ((r & 7) << 4));
}

// ---- 128x256 @ 256x256 GEMM step: A from LDS (swizzled), B packed in fragment order ----
// Packed B: element (n = nt*16 + (l&15), k = ks*32 + (l>>4)*8 + j) lives at
//           ks*8192 + nt*512 + l*8 + j   -> every fragment read is one coalesced 1KB wave load.
__device__ __forceinline__ void gemm_step(char* lds, const __bf16* wt, int lane,
                                          int m0, f32x4 acc[2][16]) {
  const int rlo = lane & 15;
  const int khi = (lane >> 4) << 3;
  const __bf16* wp = wt + lane * 8;
#pragma unroll
  for (int ks = 0; ks < 8; ++ks) {
    int kk = ks * 32 + khi;
    bf16x8 a0 = *(const bf16x8*)(lds + lds_off(m0 + rlo, 2 * kk));
    bf16x8 a1 = *(const bf16x8*)(lds + lds_off(m0 + 16 + rlo, 2 * kk));
#pragma unroll
    for (int nt = 0; nt < 16; ++nt) {
      bf16x8 b = *(const bf16x8*)(wp + ks * 8192 + nt * 512);
      acc[0][nt] = __builtin_amdgcn_mfma_f32_16x16x32_bf16(a0, b, acc[0][nt], 0, 0, 0);
      acc[1][nt] = __builtin_amdgcn_mfma_f32_16x16x32_bf16(a1, b, acc[1][nt], 0, 0, 0);
    }
  }
}

template <bool TANH, bool WRITE, bool CMAX>
__device__ __forceinline__ void epilogue(char* lds, const float* bias, int lane,
                                         int m0, f32x4 acc[2][16], float* mbuf, int wave) {
  const int rlo = lane & 15;
  const int rhi = (lane >> 4) << 2;
#pragma unroll
  for (int nt = 0; nt < 16; ++nt) {
    int c = nt * 16 + rlo;
    float bv = bias[c];
    float cm = -3.4e38f;
#pragma unroll
    for (int mt = 0; mt < 2; ++mt) {
#pragma unroll
      for (int rg = 0; rg < 4; ++rg) {
        float v = acc[mt][nt][rg] + bv;
        if (TANH) v = fast_tanh(v);
        if (WRITE) {
          int r = m0 + mt * 16 + rhi + rg;
          *(__bf16*)(lds + lds_off(r, 2 * c)) = (__bf16)v;
        }
        if (CMAX) cm = fmaxf(cm, v);
      }
    }
    if (CMAX) {
      cm = fmaxf(cm, __shfl_xor(cm, 16, 64));
      cm = fmaxf(cm, __shfl_xor(cm, 32, 64));
      if (lane < 16) mbuf[wave * 256 + c] = cm;
    }
  }
}

template <bool TANH, bool WRITE, bool CMAX>
__device__ __forceinline__ void layer256(char* lds, const __bf16* wt, const float* bias,
                                         int lane, int wave, float* mbuf) {
  f32x4 acc[2][16];
#pragma unroll
  for (int mt = 0; mt < 2; ++mt)
#pragma unroll
    for (int nt = 0; nt < 16; ++nt) acc[mt][nt] = (f32x4){0.f, 0.f, 0.f, 0.f};
  gemm_step(lds, wt, lane, wave << 5, acc);
  __syncthreads();
  epilogue<TANH, WRITE, CMAX>(lds, bias, lane, wave << 5, acc, mbuf, wave);
  __syncthreads();
}

// ------------------ weight convert/transpose/pack to bf16 + key init ------------------
struct ConvArgs { const float* src[11]; };
__global__ void K_conv(ConvArgs a, __bf16* wt, unsigned* gkeys) {
  int job = blockIdx.x;
  int t = threadIdx.x;
  if (job == 11) {
    if (blockIdx.y == 0) { gkeys[t] = 0u; gkeys[256 + t] = 0u; }
    return;
  }
  const float* s = a.src[job];
  __bf16* d = wt + (size_t)job * WT_SLOT;
#pragma unroll
  for (int it = 0; it < 16; ++it) {
    int p = blockIdx.y * 4096 + it * 256 + t;        // packed linear index
    int ks = p >> 13, nt = (p >> 9) & 15, lane = (p >> 3) & 63, j = p & 7;
    int n = nt * 16 + (lane & 15);
    int k = ks * 32 + ((lane >> 4) << 3) + j;
    d[p] = (__bf16)s[(k << 8) | n];                  // src is [K][N] fp32 (first 256 rows)
  }
}

// ------------------ big fused MLP (tb & br) + column max ------------------
struct BigArgs {
  const float* x;
  const __bf16* wt;
  const float* w0[2]; const float* b0[2];
  const float* b1[2]; const float* b2[2]; const float* b3[2];
  unsigned* gkeys;
};
__global__ __launch_bounds__(256, 2) void K_big(BigArgs a) {
  __shared__ char lds[65536];
  int tid = threadIdx.x, lane = tid & 63, wave = tid >> 6;
  int mlp = blockIdx.x >> 11;
  int row0 = (blockIdx.x & 2047) << 7;
  {  // layer0: 3 -> 256, VALU (thread t owns column t)
    const float* W0 = a.w0[mlp];
    float wa = W0[tid], wb = W0[256 + tid], wc = W0[512 + tid], bb = a.b0[mlp][tid];
    const float* xr = a.x + (size_t)row0 * 3;
#pragma unroll 4
    for (int r = 0; r < 128; ++r) {
      float v = fmaf(xr[r * 3 + 2], wc, fmaf(xr[r * 3 + 1], wb, fmaf(xr[r * 3], wa, bb)));
      *(__bf16*)(lds + lds_off(r, 2 * tid)) = (__bf16)fast_tanh(v);
    }
  }
  __syncthreads();
  const __bf16* wt = a.wt + (size_t)(mlp * 3) * WT_SLOT;
  float* mbuf = (float*)lds;
  layer256<true, true, false>(lds, wt, a.b1[mlp], lane, wave, nullptr);
  layer256<true, true, false>(lds, wt + WT_SLOT, a.b2[mlp], lane, wave, nullptr);
  layer256<false, false, true>(lds, wt + 2 * WT_SLOT, a.b3[mlp], lane, wave, mbuf);
  // cross-wave max + global atomic on ordered keys (max = commutative -> deterministic)
  float m = fmaxf(fmaxf(mbuf[tid], mbuf[256 + tid]), fmaxf(mbuf[512 + tid], mbuf[768 + tid]));
  atomicMax(a.gkeys + mlp * 256 + tid, fkey(m));
}

// ------------------ patch membership / ordered compaction ------------------
__device__ __forceinline__ bool in_patch(const float* x, int r) {
  float a = x[r * 3], b = x[r * 3 + 1], c = x[r * 3 + 2];
  int c0 = min(max((int)floorf(a * 10.0f), 0), 9);
  int c1 = min(max((int)floorf(b * 10.0f), 0), 9);
  int c2 = min(max((int)floorf(c * 10.0f), 0), 9);
  return (c0 == 9) && (c1 == 9) && (c2 == 5);  // patch id 995
}
__global__ void K_count(const float* x, unsigned* counts) {
  __shared__ unsigned sw[4];
  int b = blockIdx.x, t = threadIdx.x;
  int base = b * 1024 + t * 4;
  unsigned c = 0;
#pragma unroll
  for (int j = 0; j < 4; ++j) c += in_patch(x, base + j) ? 1u : 0u;
#pragma unroll
  for (int o = 1; o < 64; o <<= 1) c += __shfl_xor((int)c, o, 64);
  if ((t & 63) == 0) sw[t >> 6] = c;
  __syncthreads();
  if (t == 0) counts[b] = sw[0] + sw[1] + sw[2] + sw[3];
}
__global__ void K_scan(const unsigned* counts, unsigned* bases) {
  __shared__ unsigned s[256];
  int t = threadIdx.x;
  unsigned c = counts[t];
  s[t] = c; __syncthreads();
  for (int o = 1; o < 256; o <<= 1) {
    unsigned v = (t >= o) ? s[t - o] : 0u;
    __syncthreads();
    s[t] += v;
    __syncthreads();
  }
  bases[t] = s[t] - c;
}
__global__ void K_fill(const float* x, const unsigned* bases, int* idx) {
  __shared__ unsigned s[256];
  int b = blockIdx.x, t = threadIdx.x;
  int base = b * 1024 + t * 4;
  unsigned fm = 0, c = 0;
#pragma unroll
  for (int j = 0; j < 4; ++j) {
    bool f = in_patch(x, base + j);
    fm |= (f ? 1u : 0u) << j;
    c += f ? 1u : 0u;
  }
  s[t] = c; __syncthreads();
  for (int o = 1; o < 256; o <<= 1) {
    unsigned v = (t >= o) ? s[t - o] : 0u;
    __syncthreads();
    s[t] += v;
    __syncthreads();
  }
  unsigned pos = bases[b] + s[t] - c;
#pragma unroll
  for (int j = 0; j < 4; ++j)
    if (fm & (1u << j)) idx[pos++] = base + j;
}

// ------------------ finalize params + broadcast part of o-layer1 ------------------
__global__ void K_vec(const unsigned* gkeys, const float* ow0, const float* ob0, float* vec0) {
  __shared__ float gp[256], lp[256];
  int t = threadIdx.x;
  gp[t] = unfkey(gkeys[t]);        // tb -> global_param
  lp[t] = unfkey(gkeys[256 + t]);  // br -> local_param
  __syncthreads();
  float acc = ob0[t];
  for (int k = 0; k < 256; ++k) {
    acc = fmaf(lp[k], ow0[(256 + k) * 256 + t], acc);
    acc = fmaf(gp[k], ow0[(512 + k) * 256 + t], acc);
  }
  vec0[t] = acc;
}

// ------------------ patch pipeline: tr-MLP + out-MLP + gt copy ------------------
struct SmallArgs {
  const float* x; const float* y; const int* idx; int MM;
  const __bf16* wt;
  const float* trw0; const float* trb0;
  const float* trb1; const float* trb2; const float* trb3;
  const float* vec0; const float* ob1; const float* ow2; const float* ob2;
  float* out;
};
__global__ __launch_bounds__(256, 2) void K_small(SmallArgs a) {
  __shared__ char lds[65536];
  int tid = threadIdx.x, lane = tid & 63, wave = tid >> 6;
  int pr0 = blockIdx.x << 7;
  {  // gather x_patch, write gt (fp32 exact), layer0 of tr (thread pair (r,half) owns row r)
    int r = tid >> 1, half = tid & 1;
    int pr = pr0 + r;
    int j = a.idx[min(pr, a.MM - 1)];
    if (half == 0 && pr < a.MM) a.out[a.MM + pr] = a.y[j];
    float x0 = a.x[j * 3], x1 = a.x[j * 3 + 1], x2 = a.x[j * 3 + 2];
    for (int i = 0; i < 128; ++i) {
      int c = (half << 7) + i;
      float v = fmaf(x2, a.trw0[512 + c], fmaf(x1, a.trw0[256 + c], fmaf(x0, a.trw0[c], a.trb0[c])));
      *(__bf16*)(lds + lds_off(r, 2 * c)) = (__bf16)fast_tanh(v);
    }
  }
  __syncthreads();
  const __bf16* wt_tr = a.wt + (size_t)6 * WT_SLOT;
  layer256<true, true, false>(lds, wt_tr, a.trb1, lane, wave, nullptr);
  layer256<true, true, false>(lds, wt_tr + WT_SLOT, a.trb2, lane, wave, nullptr);
  layer256<false, true, false>(lds, wt_tr + 2 * WT_SLOT, a.trb3, lane, wave, nullptr);  // local_coord
  layer256<true, true, false>(lds, a.wt + (size_t)9 * WT_SLOT, a.vec0, lane, wave, nullptr);  // o1
  layer256<true, true, false>(lds, a.wt + (size_t)10 * WT_SLOT, a.ob1, lane, wave, nullptr);  // o2
  {  // o3: 256 -> 1 dot per row, fp32 out
    int r = tid >> 1, half = tid & 1, pr = pr0 + r;
    float s = 0.f;
    for (int i = 0; i < 128; ++i) {
      int c = (half << 7) + i;
      s = fmaf((float)*(const __bf16*)(lds + lds_off(r, 2 * c)), a.ow2[c], s);
    }
    s += __shfl_xor(s, 1, 64);
    if (half == 0 && pr < a.MM) a.out[pr] = s + a.ob2[0];
  }
}

extern "C" void kernel_launch(void* const* d_in, const int* in_sizes, int n_in,
                              void* d_out, int out_size, void* d_ws, size_t ws_size,
                              hipStream_t stream) {
  const float* x = (const float*)d_in[0];
  const float* y = (const float*)d_in[1];
  char* ws = (char*)d_ws;
  unsigned* gkeys = (unsigned*)(ws + WS_GKEYS);
  float* vec0 = (float*)(ws + WS_VEC0);
  unsigned* counts = (unsigned*)(ws + WS_COUNTS);
  unsigned* bases = (unsigned*)(ws + WS_BASES);
  int* idx = (int*)(ws + WS_IDX);
  __bf16* wt = (__bf16*)(ws + WS_WT);
  int MM = out_size / 2;

  ConvArgs ca;
  for (int m = 0; m < 3; ++m)           // 0=tb,1=br,2=tr ; L -> w_{L+1}
    for (int L = 0; L < 3; ++L)
      ca.src[m * 3 + L] = (const float*)d_in[2 + m * 8 + 2 * (L + 1)];
  ca.src[9] = (const float*)d_in[26];   // o_w0 (top 256 rows used)
  ca.src[10] = (const float*)d_in[28];  // o_w1
  hipLaunchKernelGGL(K_conv, dim3(12, 16), dim3(256), 0, stream, ca, wt, gkeys);

  K_count<<<256, 256, 0, stream>>>(x, counts);
  K_scan<<<1, 256, 0, stream>>>(counts, bases);
  K_fill<<<256, 256, 0, stream>>>(x, bases, idx);

  BigArgs ba;
  ba.x = x; ba.wt = wt; ba.gkeys = gkeys;
  ba.w0[0] = (const float*)d_in[2];  ba.b0[0] = (const float*)d_in[3];
  ba.b1[0] = (const float*)d_in[5];  ba.b2[0] = (const float*)d_in[7];  ba.b3[0] = (const float*)d_in[9];
  ba.w0[1] = (const float*)d_in[10]; ba.b0[1] = (const float*)d_in[11];
  ba.b1[1] = (const float*)d_in[13]; ba.b2[1] = (const float*)d_in[15]; ba.b3[1] = (const float*)d_in[17];
  K_big<<<4096, 256, 0, stream>>>(ba);

  K_vec<<<1, 256, 0, stream>>>(gkeys, (const float*)d_in[26], (const float*)d_in[27], vec0);

  if (MM > 0) {
    SmallArgs sa;
    sa.x = x; sa.y = y; sa.idx = idx; sa.MM = MM; sa.wt = wt;
    sa.trw0 = (const float*)d_in[18]; sa.trb0 = (const float*)d_in[19];
    sa.trb1 = (const float*)d_in[21]; sa.trb2 = (const float*)d_in[23]; sa.trb3 = (const float*)d_in[25];
    sa.vec0 = vec0;
    sa.ob1 = (const float*)d_in[29];
    sa.ow2 = (const float*)d_in[30]; sa.ob2 = (const float*)d_in[31];
    sa.out = (float*)d_out;
    K_small<<<(MM + 127) / 128, 256, 0, stream>>>(sa);
  }
}

// Round 4
// 435.075 us; speedup vs baseline: 2.7438x; 1.9622x over previous
//
#include <hip/hip_runtime.h>

typedef __bf16 bf16x8 __attribute__((ext_vector_type(8)));
typedef float f32x4 __attribute__((ext_vector_type(4)));

#define WT_SLOT 65536              // elements per 256x256 bf16 weight slot (packed fragment order)
#define WS_GKEYS 0                 // 512 u32 (tb keys, br keys)
#define WS_VEC0  4096              // 256 f32
#define WS_COUNTS 8192             // 256 u32
#define WS_BASES 12288             // 256 u32
#define WS_IDX   16384             // 4096 i32
#define WS_WT    32768             // 11 slots * 131072 B

__device__ __forceinline__ float fast_tanh(float x) {
  float e = __builtin_amdgcn_exp2f(x * 2.8853900817779268f); // exp(2x)
  return 1.0f - 2.0f * __builtin_amdgcn_rcpf(e + 1.0f);
}
__device__ __forceinline__ unsigned fkey(float f) {
  unsigned u = __float_as_uint(f);
  return (u & 0x80000000u) ? ~u : (u | 0x80000000u);
}
__device__ __forceinline__ float unfkey(unsigned k) {
  unsigned u = (k & 0x80000000u) ? (k & 0x7FFFFFFFu) : ~k;
  return __uint_as_float(u);
}
// swizzled LDS byte offset for a [128][256] bf16 tile, row stride 512B
__device__ __forceinline__ int lds_off(int r, int cb) {
  return r * 512 + (cb ^ ((r & 7) << 4));
}

// Packed B layout: element (n = nt*16 + (l&15), k = ks*32 + (l>>4)*8 + j) at
// linear ks*8192 + nt*512 + l*8 + j. Wave w owns nt = 4w..4w+3 (cols 64w..64w+63).
// Load one ks-pair (2 ks x 4 nt = 8 fragments = 32 VGPRs) for this wave.
__device__ __forceinline__ void load_bpair(const __bf16* wt, int wave, int lane, int p,
                                           bf16x8 b[8]) {
  const __bf16* base = wt + p * 16384 + wave * 2048 + lane * 8;
#pragma unroll
  for (int h = 0; h < 2; ++h)
#pragma unroll
    for (int i = 0; i < 4; ++i)
      b[h * 4 + i] = *(const bf16x8*)(base + h * 8192 + i * 512);
}

__device__ __forceinline__ void compute_pair(char* lds, const bf16x8 bc[8], int ksbase,
                                             int rlo, int khi, f32x4 acc[8][4]) {
#pragma unroll
  for (int h = 0; h < 2; ++h) {
    int cb = (ksbase + h) * 64 + 2 * khi;   // byte column of this k-chunk
#pragma unroll
    for (int rt = 0; rt < 8; ++rt) {
      bf16x8 a = *(const bf16x8*)(lds + lds_off(rt * 16 + rlo, cb));
#pragma unroll
      for (int i = 0; i < 4; ++i)
        acc[rt][i] = __builtin_amdgcn_mfma_f32_16x16x32_bf16(a, bc[h * 4 + i], acc[rt][i], 0, 0, 0);
    }
  }
}

// One 256->256 layer: A (128x256 act tile) from LDS, B register-double-buffered.
// Precondition: b0 holds THIS layer's pair0. Postcondition: b0 holds wt_next's pair0.
template <bool TANH, bool WRITE, bool CMAX>
__device__ __forceinline__ void layer256(char* lds, const __bf16* wt, const __bf16* wt_next,
                                         const float* bias, int lane, int wave, float* mbuf,
                                         bf16x8 b0[8], bf16x8 b1[8]) {
  const int rlo = lane & 15;
  const int khi = (lane >> 4) << 3;
  f32x4 acc[8][4];
#pragma unroll
  for (int rt = 0; rt < 8; ++rt)
#pragma unroll
    for (int i = 0; i < 4; ++i) acc[rt][i] = (f32x4){0.f, 0.f, 0.f, 0.f};

  load_bpair(wt, wave, lane, 1, b1);
  compute_pair(lds, b0, 0, rlo, khi, acc);
  load_bpair(wt, wave, lane, 2, b0);
  compute_pair(lds, b1, 2, rlo, khi, acc);
  load_bpair(wt, wave, lane, 3, b1);
  compute_pair(lds, b0, 4, rlo, khi, acc);
  load_bpair(wt_next, wave, lane, 0, b0);   // prefetch next layer's pair0
  compute_pair(lds, b1, 6, rlo, khi, acc);

  __syncthreads();                          // all act-tile reads done before overwrite
  const int rhi = (lane >> 4) << 2;
#pragma unroll
  for (int i = 0; i < 4; ++i) {
    int c = (wave * 4 + i) * 16 + rlo;
    float bv = bias[c];
    float cm = -3.4e38f;
#pragma unroll
    for (int rt = 0; rt < 8; ++rt) {
#pragma unroll
      for (int rg = 0; rg < 4; ++rg) {
        float v = acc[rt][i][rg] + bv;
        if (TANH) v = fast_tanh(v);
        if (WRITE) *(__bf16*)(lds + lds_off(rt * 16 + rhi + rg, 2 * c)) = (__bf16)v;
        if (CMAX) cm = fmaxf(cm, v);
      }
    }
    if (CMAX) {  // wave owns its 64 cols exclusively: reduce row-groups, write col max
      cm = fmaxf(cm, __shfl_xor(cm, 16, 64));
      cm = fmaxf(cm, __shfl_xor(cm, 32, 64));
      if (lane < 16) mbuf[c] = cm;
    }
  }
  __syncthreads();
}

// ------------------ weight convert/transpose/pack to bf16 + key init ------------------
struct ConvArgs { const float* src[11]; };
__global__ void K_conv(ConvArgs a, __bf16* wt, unsigned* gkeys) {
  int job = blockIdx.x;
  int t = threadIdx.x;
  if (job == 11) {
    if (blockIdx.y == 0) { gkeys[t] = 0u; gkeys[256 + t] = 0u; }
    return;
  }
  const float* s = a.src[job];
  __bf16* d = wt + (size_t)job * WT_SLOT;
#pragma unroll
  for (int it = 0; it < 16; ++it) {
    int p = blockIdx.y * 4096 + it * 256 + t;        // packed linear index
    int ks = p >> 13, nt = (p >> 9) & 15, lane = (p >> 3) & 63, j = p & 7;
    int n = nt * 16 + (lane & 15);
    int k = ks * 32 + ((lane >> 4) << 3) + j;
    d[p] = (__bf16)s[(k << 8) | n];                  // src is [K][N] fp32 (first 256 rows)
  }
}

// ------------------ big fused MLP (tb & br) + column max ------------------
struct BigArgs {
  const float* x;
  const __bf16* wt;
  const float* w0[2]; const float* b0[2];
  const float* b1[2]; const float* b2[2]; const float* b3[2];
  unsigned* gkeys;
};
__global__ __launch_bounds__(256, 2) void K_big(BigArgs a) {
  __shared__ char lds[65536];
  int tid = threadIdx.x, lane = tid & 63, wave = tid >> 6;
  int mlp = blockIdx.x >> 11;
  int row0 = (blockIdx.x & 2047) << 7;
  const __bf16* wt = a.wt + (size_t)(mlp * 3) * WT_SLOT;
  bf16x8 br0[8], br1[8];
  load_bpair(wt, wave, lane, 0, br0);     // prefetch layer-1 pair0 under layer-0 VALU
  {  // layer0: 3 -> 256, VALU (thread t owns column t)
    const float* W0 = a.w0[mlp];
    float wa = W0[tid], wb = W0[256 + tid], wc = W0[512 + tid], bb = a.b0[mlp][tid];
    const float* xr = a.x + (size_t)row0 * 3;
#pragma unroll 4
    for (int r = 0; r < 128; ++r) {
      float v = fmaf(xr[r * 3 + 2], wc, fmaf(xr[r * 3 + 1], wb, fmaf(xr[r * 3], wa, bb)));
      *(__bf16*)(lds + lds_off(r, 2 * tid)) = (__bf16)fast_tanh(v);
    }
  }
  __syncthreads();
  float* mbuf = (float*)lds;
  layer256<true, true, false>(lds, wt, wt + WT_SLOT, a.b1[mlp], lane, wave, nullptr, br0, br1);
  layer256<true, true, false>(lds, wt + WT_SLOT, wt + 2 * WT_SLOT, a.b2[mlp], lane, wave, nullptr, br0, br1);
  layer256<false, false, true>(lds, wt + 2 * WT_SLOT, wt + 2 * WT_SLOT, a.b3[mlp], lane, wave, mbuf, br0, br1);
  // each col's block-max is in mbuf; one atomic per column (max = commutative -> deterministic)
  atomicMax(a.gkeys + mlp * 256 + tid, fkey(mbuf[tid]));
}

// ------------------ patch membership / ordered compaction ------------------
__device__ __forceinline__ bool in_patch(const float* x, int r) {
  float a = x[r * 3], b = x[r * 3 + 1], c = x[r * 3 + 2];
  int c0 = min(max((int)floorf(a * 10.0f), 0), 9);
  int c1 = min(max((int)floorf(b * 10.0f), 0), 9);
  int c2 = min(max((int)floorf(c * 10.0f), 0), 9);
  return (c0 == 9) && (c1 == 9) && (c2 == 5);  // patch id 995
}
__global__ void K_count(const float* x, unsigned* counts) {
  __shared__ unsigned sw[4];
  int b = blockIdx.x, t = threadIdx.x;
  int base = b * 1024 + t * 4;
  unsigned c = 0;
#pragma unroll
  for (int j = 0; j < 4; ++j) c += in_patch(x, base + j) ? 1u : 0u;
#pragma unroll
  for (int o = 1; o < 64; o <<= 1) c += __shfl_xor((int)c, o, 64);
  if ((t & 63) == 0) sw[t >> 6] = c;
  __syncthreads();
  if (t == 0) counts[b] = sw[0] + sw[1] + sw[2] + sw[3];
}
__global__ void K_scan(const unsigned* counts, unsigned* bases) {
  __shared__ unsigned s[256];
  int t = threadIdx.x;
  unsigned c = counts[t];
  s[t] = c; __syncthreads();
  for (int o = 1; o < 256; o <<= 1) {
    unsigned v = (t >= o) ? s[t - o] : 0u;
    __syncthreads();
    s[t] += v;
    __syncthreads();
  }
  bases[t] = s[t] - c;
}
__global__ void K_fill(const float* x, const unsigned* bases, int* idx) {
  __shared__ unsigned s[256];
  int b = blockIdx.x, t = threadIdx.x;
  int base = b * 1024 + t * 4;
  unsigned fm = 0, c = 0;
#pragma unroll
  for (int j = 0; j < 4; ++j) {
    bool f = in_patch(x, base + j);
    fm |= (f ? 1u : 0u) << j;
    c += f ? 1u : 0u;
  }
  s[t] = c; __syncthreads();
  for (int o = 1; o < 256; o <<= 1) {
    unsigned v = (t >= o) ? s[t - o] : 0u;
    __syncthreads();
    s[t] += v;
    __syncthreads();
  }
  unsigned pos = bases[b] + s[t] - c;
#pragma unroll
  for (int j = 0; j < 4; ++j)
    if (fm & (1u << j)) idx[pos++] = base + j;
}

// ------------------ finalize params + broadcast part of o-layer1 ------------------
__global__ void K_vec(const unsigned* gkeys, const float* ow0, const float* ob0, float* vec0) {
  __shared__ float gp[256], lp[256];
  int t = threadIdx.x;
  gp[t] = unfkey(gkeys[t]);        // tb -> global_param
  lp[t] = unfkey(gkeys[256 + t]);  // br -> local_param
  __syncthreads();
  float acc = ob0[t];
  for (int k = 0; k < 256; ++k) {
    acc = fmaf(lp[k], ow0[(256 + k) * 256 + t], acc);
    acc = fmaf(gp[k], ow0[(512 + k) * 256 + t], acc);
  }
  vec0[t] = acc;
}

// ------------------ patch pipeline: tr-MLP + out-MLP + gt copy ------------------
struct SmallArgs {
  const float* x; const float* y; const int* idx; int MM;
  const __bf16* wt;
  const float* trw0; const float* trb0;
  const float* trb1; const float* trb2; const float* trb3;
  const float* vec0; const float* ob1; const float* ow2; const float* ob2;
  float* out;
};
__global__ __launch_bounds__(256, 2) void K_small(SmallArgs a) {
  __shared__ char lds[65536];
  int tid = threadIdx.x, lane = tid & 63, wave = tid >> 6;
  int pr0 = blockIdx.x << 7;
  const __bf16* wt6 = a.wt + (size_t)6 * WT_SLOT;
  bf16x8 br0[8], br1[8];
  load_bpair(wt6, wave, lane, 0, br0);
  {  // gather x_patch, write gt (fp32 exact), layer0 of tr (thread pair (r,half) owns row r)
    int r = tid >> 1, half = tid & 1;
    int pr = pr0 + r;
    int j = a.idx[min(pr, a.MM - 1)];
    if (half == 0 && pr < a.MM) a.out[a.MM + pr] = a.y[j];
    float x0 = a.x[j * 3], x1 = a.x[j * 3 + 1], x2 = a.x[j * 3 + 2];
    for (int i = 0; i < 128; ++i) {
      int c = (half << 7) + i;
      float v = fmaf(x2, a.trw0[512 + c], fmaf(x1, a.trw0[256 + c], fmaf(x0, a.trw0[c], a.trb0[c])));
      *(__bf16*)(lds + lds_off(r, 2 * c)) = (__bf16)fast_tanh(v);
    }
  }
  __syncthreads();
  layer256<true, true, false>(lds, wt6, wt6 + WT_SLOT, a.trb1, lane, wave, nullptr, br0, br1);
  layer256<true, true, false>(lds, wt6 + WT_SLOT, wt6 + 2 * WT_SLOT, a.trb2, lane, wave, nullptr, br0, br1);
  layer256<false, true, false>(lds, wt6 + 2 * WT_SLOT, wt6 + 3 * WT_SLOT, a.trb3, lane, wave, nullptr, br0, br1);  // local_coord
  layer256<true, true, false>(lds, wt6 + 3 * WT_SLOT, wt6 + 4 * WT_SLOT, a.vec0, lane, wave, nullptr, br0, br1);   // o1
  layer256<true, true, false>(lds, wt6 + 4 * WT_SLOT, wt6 + 4 * WT_SLOT, a.ob1, lane, wave, nullptr, br0, br1);    // o2
  {  // o3: 256 -> 1 dot per row, fp32 out
    int r = tid >> 1, half = tid & 1, pr = pr0 + r;
    float s = 0.f;
    for (int i = 0; i < 128; ++i) {
      int c = (half << 7) + i;
      s = fmaf((float)*(const __bf16*)(lds + lds_off(r, 2 * c)), a.ow2[c], s);
    }
    s += __shfl_xor(s, 1, 64);
    if (half == 0 && pr < a.MM) a.out[pr] = s + a.ob2[0];
  }
}

extern "C" void kernel_launch(void* const* d_in, const int* in_sizes, int n_in,
                              void* d_out, int out_size, void* d_ws, size_t ws_size,
                              hipStream_t stream) {
  const float* x = (const float*)d_in[0];
  const float* y = (const float*)d_in[1];
  char* ws = (char*)d_ws;
  unsigned* gkeys = (unsigned*)(ws + WS_GKEYS);
  float* vec0 = (float*)(ws + WS_VEC0);
  unsigned* counts = (unsigned*)(ws + WS_COUNTS);
  unsigned* bases = (unsigned*)(ws + WS_BASES);
  int* idx = (int*)(ws + WS_IDX);
  __bf16* wt = (__bf16*)(ws + WS_WT);
  int MM = out_size / 2;

  ConvArgs ca;
  for (int m = 0; m < 3; ++m)           // 0=tb,1=br,2=tr ; L -> w_{L+1}
    for (int L = 0; L < 3; ++L)
      ca.src[m * 3 + L] = (const float*)d_in[2 + m * 8 + 2 * (L + 1)];
  ca.src[9] = (const float*)d_in[26];   // o_w0 (top 256 rows used)
  ca.src[10] = (const float*)d_in[28];  // o_w1
  hipLaunchKernelGGL(K_conv, dim3(12, 16), dim3(256), 0, stream, ca, wt, gkeys);

  K_count<<<256, 256, 0, stream>>>(x, counts);
  K_scan<<<1, 256, 0, stream>>>(counts, bases);
  K_fill<<<256, 256, 0, stream>>>(x, bases, idx);

  BigArgs ba;
  ba.x = x; ba.wt = wt; ba.gkeys = gkeys;
  ba.w0[0] = (const float*)d_in[2];  ba.b0[0] = (const float*)d_in[3];
  ba.b1[0] = (const float*)d_in[5];  ba.b2[0] = (const float*)d_in[7];  ba.b3[0] = (const float*)d_in[9];
  ba.w0[1] = (const float*)d_in[10]; ba.b0[1] = (const float*)d_in[11];
  ba.b1[1] = (const float*)d_in[13]; ba.b2[1] = (const float*)d_in[15]; ba.b3[1] = (const float*)d_in[17];
  K_big<<<4096, 256, 0, stream>>>(ba);

  K_vec<<<1, 256, 0, stream>>>(gkeys, (const float*)d_in[26], (const float*)d_in[27], vec0);

  if (MM > 0) {
    SmallArgs sa;
    sa.x = x; sa.y = y; sa.idx = idx; sa.MM = MM; sa.wt = wt;
    sa.trw0 = (const float*)d_in[18]; sa.trb0 = (const float*)d_in[19];
    sa.trb1 = (const float*)d_in[21]; sa.trb2 = (const float*)d_in[23]; sa.trb3 = (const float*)d_in[25];
    sa.vec0 = vec0;
    sa.ob1 = (const float*)d_in[29];
    sa.ow2 = (const float*)d_in[30]; sa.ob2 = (const float*)d_in[31];
    sa.out = (float*)d_out;
    K_small<<<(MM + 127) / 128, 256, 0, stream>>>(sa);
  }
}

// Round 5
// 278.806 us; speedup vs baseline: 4.2817x; 1.5605x over previous
//
#include <hip/hip_runtime.h>

typedef __bf16 bf16x8 __attribute__((ext_vector_type(8)));
typedef __bf16 bf16x4 __attribute__((ext_vector_type(4)));
typedef float f32x4 __attribute__((ext_vector_type(4)));

#define WT_SLOT 65536              // elements per 256x256 bf16 weight slot (packed fragment order)
#define WS_GKEYS 0                 // 512 u32 (tb keys, br keys)
#define WS_VEC0  4096              // 256 f32
#define WS_COUNTS 8192             // 256 u32
#define WS_BASES 12288             // 256 u32
#define WS_IDX   16384             // 4096 i32
#define WS_WT    32768             // 12 slots * 131072 B (slot 11 = 3 packed-W0 minis)

__device__ __forceinline__ float fast_tanh(float x) {
  float e = __builtin_amdgcn_exp2f(x * 2.8853900817779268f); // exp(2x)
  return 1.0f - 2.0f * __builtin_amdgcn_rcpf(e + 1.0f);
}
__device__ __forceinline__ unsigned fkey(float f) {
  unsigned u = __float_as_uint(f);
  return (u & 0x80000000u) ? ~u : (u | 0x80000000u);
}
__device__ __forceinline__ float unfkey(unsigned k) {
  unsigned u = (k & 0x80000000u) ? (k & 0x7FFFFFFFu) : ~k;
  return __uint_as_float(u);
}
// swizzled LDS byte offset for a [128][256] bf16 tile, row stride 512B
__device__ __forceinline__ int lds_off(int r, int cb) {
  return r * 512 + (cb ^ ((r & 7) << 4));
}

// Packed B layout: element (n = nt*16 + (l&15), k = ks*32 + (l>>4)*8 + j) at
// linear ks*8192 + nt*512 + l*8 + j. Wave w owns nt = 4w..4w+3 (cols 64w..64w+63).
__device__ __forceinline__ void load_bpair(const __bf16* wt, int wave, int lane, int p,
                                           bf16x8 b[8]) {
  const __bf16* base = wt + p * 16384 + wave * 2048 + lane * 8;
#pragma unroll
  for (int h = 0; h < 2; ++h)
#pragma unroll
    for (int i = 0; i < 4; ++i)
      b[h * 4 + i] = *(const bf16x8*)(base + h * 8192 + i * 512);
}

// Swapped-operand MFMA: mfma(W_frag, A_frag, acc) -> D[m=weight-col][n=act-row],
// lane holds rows r = rt*16 + (lane&15), cols cbase + (lane>>4)*4 + rg (4 consecutive).
__device__ __forceinline__ void compute_pair(char* lds, const bf16x8 bc[8], int ksbase,
                                             int rlo, int khi2, f32x4 acc[8][4]) {
#pragma unroll
  for (int h = 0; h < 2; ++h) {
    int cb = (ksbase + h) * 64 + khi2;   // byte column of this k-chunk
#pragma unroll
    for (int rt = 0; rt < 8; ++rt) {
      bf16x8 av = *(const bf16x8*)(lds + lds_off(rt * 16 + rlo, cb));
#pragma unroll
      for (int i = 0; i < 4; ++i)
        acc[rt][i] = __builtin_amdgcn_mfma_f32_16x16x32_bf16(bc[h * 4 + i], av, acc[rt][i], 0, 0, 0);
    }
  }
}

template <bool TANH, bool WRITE, bool CMAX>
__device__ __forceinline__ void epilogue(char* lds, const float* bias, int lane, int wave,
                                         f32x4 acc[8][4], float* mbuf) {
  const int rlo = lane & 15;
  const int q4 = (lane >> 4) << 2;
#pragma unroll
  for (int i = 0; i < 4; ++i) {
    const int cbase = (wave * 4 + i) * 16 + q4;       // 4 consecutive cols per lane
    f32x4 bv = *(const f32x4*)(bias + cbase);
    f32x4 cm;
#pragma unroll
    for (int rt = 0; rt < 8; ++rt) {
      f32x4 v;
#pragma unroll
      for (int rg = 0; rg < 4; ++rg) {
        float t = acc[rt][i][rg] + bv[rg];
        if (TANH) t = fast_tanh(t);
        v[rg] = t;
      }
      if (WRITE) {
        bf16x4 pv;
#pragma unroll
        for (int rg = 0; rg < 4; ++rg) pv[rg] = (__bf16)v[rg];
        *(bf16x4*)(lds + lds_off(rt * 16 + rlo, 2 * cbase)) = pv;
      }
      if (CMAX) {
        if (rt == 0) cm = v;
        else {
#pragma unroll
          for (int rg = 0; rg < 4; ++rg) cm[rg] = fmaxf(cm[rg], v[rg]);
        }
      }
    }
    if (CMAX) {  // reduce over rows (lane&15 across lanes), cols distinct per (q,rg)
#pragma unroll
      for (int rg = 0; rg < 4; ++rg) {
#pragma unroll
        for (int off = 1; off <= 8; off <<= 1)
          cm[rg] = fmaxf(cm[rg], __shfl_xor(cm[rg], off, 64));
      }
      if (rlo == 0) *(f32x4*)(mbuf + cbase) = cm;
    }
  }
}

// One 256->256 layer. Precondition: b0 holds THIS layer's pair0. Post: b0 holds wt_next pair0.
template <bool TANH, bool WRITE, bool CMAX>
__device__ __forceinline__ void layer256(char* lds, const __bf16* wt, const __bf16* wt_next,
                                         const float* bias, int lane, int wave, float* mbuf,
                                         bf16x8 b0[8], bf16x8 b1[8]) {
  const int rlo = lane & 15;
  const int khi2 = (lane >> 4) << 4;   // byte offset of k-subrange
  f32x4 acc[8][4];
#pragma unroll
  for (int rt = 0; rt < 8; ++rt)
#pragma unroll
    for (int i = 0; i < 4; ++i) acc[rt][i] = (f32x4){0.f, 0.f, 0.f, 0.f};

  load_bpair(wt, wave, lane, 1, b1);
  compute_pair(lds, b0, 0, rlo, khi2, acc);
  load_bpair(wt, wave, lane, 2, b0);
  compute_pair(lds, b1, 2, rlo, khi2, acc);
  load_bpair(wt, wave, lane, 3, b1);
  compute_pair(lds, b0, 4, rlo, khi2, acc);
  load_bpair(wt_next, wave, lane, 0, b0);   // prefetch next layer's pair0
  compute_pair(lds, b1, 6, rlo, khi2, acc);

  __syncthreads();                          // all act-tile reads done before overwrite
  epilogue<TANH, WRITE, CMAX>(lds, bias, lane, wave, acc, mbuf);
  __syncthreads();
}

// layer0 (K=32) via MFMA on the mini x-tile; b0f = 4 packed W0 fragments
template <bool TANH>
__device__ __forceinline__ void layer0_mfma(char* lds, const char* mini, const bf16x8 b0f[4],
                                            const float* bias, int lane, int wave) {
  const int rlo = lane & 15;
  const int khi2 = (lane >> 4) << 4;
  f32x4 acc[8][4];
#pragma unroll
  for (int rt = 0; rt < 8; ++rt)
#pragma unroll
    for (int i = 0; i < 4; ++i) acc[rt][i] = (f32x4){0.f, 0.f, 0.f, 0.f};
#pragma unroll
  for (int rt = 0; rt < 8; ++rt) {
    bf16x8 av = *(const bf16x8*)(mini + (rt * 16 + rlo) * 64 + khi2);
#pragma unroll
    for (int i = 0; i < 4; ++i)
      acc[rt][i] = __builtin_amdgcn_mfma_f32_16x16x32_bf16(b0f[i], av, acc[rt][i], 0, 0, 0);
  }
  epilogue<TANH, true, false>(lds, bias, lane, wave, acc, nullptr);
  __syncthreads();
}

// ------------------ weight convert/transpose/pack to bf16 + key init ------------------
struct ConvArgs { const float* src[14]; };
__global__ void K_conv(ConvArgs a, __bf16* wt, unsigned* gkeys) {
  int job = blockIdx.x, t = threadIdx.x, y = blockIdx.y;
  if (job == 14) {
    if (y == 0) { gkeys[t] = 0u; gkeys[256 + t] = 0u; }
    return;
  }
  if (job >= 11) {  // W0 minis: (3,256) fp32 -> one K=32 fragment chunk, zero-padded
    if (y >= 2) return;
    const float* s = a.src[job];
    __bf16* d = wt + (size_t)11 * WT_SLOT + (job - 11) * 8192;
#pragma unroll
    for (int it = 0; it < 16; ++it) {
      int p = y * 4096 + it * 256 + t;
      int nt = (p >> 9) & 15, ln = (p >> 3) & 63, j = p & 7;
      int n = nt * 16 + (ln & 15);
      int k = ((ln >> 4) << 3) + j;
      d[p] = (k < 3) ? (__bf16)s[k * 256 + n] : (__bf16)0.f;
    }
    return;
  }
  const float* s = a.src[job];
  __bf16* d = wt + (size_t)job * WT_SLOT;
#pragma unroll
  for (int it = 0; it < 16; ++it) {
    int p = y * 4096 + it * 256 + t;                 // packed linear index
    int ks = p >> 13, nt = (p >> 9) & 15, ln = (p >> 3) & 63, j = p & 7;
    int n = nt * 16 + (ln & 15);
    int k = ks * 32 + ((ln >> 4) << 3) + j;
    d[p] = (__bf16)s[(k << 8) | n];                  // src is [K][N] fp32 (first 256 rows)
  }
}

// ------------------ big fused MLP (tb & br) + column max ------------------
struct BigArgs {
  const float* x;
  const __bf16* wt;
  const float* b0[2]; const float* b1[2]; const float* b2[2]; const float* b3[2];
  unsigned* gkeys;
};
__global__ __launch_bounds__(256, 2) void K_big(BigArgs a) {
  __shared__ char lds[73728];          // 64KB act tile + 8KB mini x-tile
  int tid = threadIdx.x, lane = tid & 63, wave = tid >> 6;
  int mlp = blockIdx.x >> 11;
  int row0 = (blockIdx.x & 2047) << 7;
  const __bf16* wt = a.wt + (size_t)(mlp * 3) * WT_SLOT;
  const __bf16* w0f = a.wt + (size_t)11 * WT_SLOT + mlp * 8192;
  char* mini = lds + 65536;
  {  // stage x -> bf16 mini tile [128][32] (k=0..2 data, rest zeros)
    const float* xr = a.x + (size_t)row0 * 3;
    for (int s = tid; s < 512; s += 256) {
      int r = s & 127, ch = s >> 7;
      bf16x8 v;
#pragma unroll
      for (int j = 0; j < 8; ++j) v[j] = (__bf16)0.f;
      if (ch == 0) {
        v[0] = (__bf16)xr[r * 3]; v[1] = (__bf16)xr[r * 3 + 1]; v[2] = (__bf16)xr[r * 3 + 2];
      }
      *(bf16x8*)(mini + r * 64 + ch * 16) = v;
    }
  }
  bf16x8 b0f[4];
#pragma unroll
  for (int i = 0; i < 4; ++i) b0f[i] = *(const bf16x8*)(w0f + (wave * 4 + i) * 512 + lane * 8);
  bf16x8 br0[8], br1[8];
  load_bpair(wt, wave, lane, 0, br0);   // prefetch layer-1 pair0
  __syncthreads();
  layer0_mfma<true>(lds, mini, b0f, a.b0[mlp], lane, wave);
  float* mbuf = (float*)mini;           // mini region free after layer0
  layer256<true, true, false>(lds, wt, wt + WT_SLOT, a.b1[mlp], lane, wave, nullptr, br0, br1);
  layer256<true, true, false>(lds, wt + WT_SLOT, wt + 2 * WT_SLOT, a.b2[mlp], lane, wave, nullptr, br0, br1);
  layer256<false, false, true>(lds, wt + 2 * WT_SLOT, wt + 2 * WT_SLOT, a.b3[mlp], lane, wave, mbuf, br0, br1);
  // per-column block max -> one atomic per column (max = commutative -> deterministic)
  atomicMax(a.gkeys + mlp * 256 + tid, fkey(mbuf[tid]));
}

// ------------------ patch membership / ordered compaction ------------------
__device__ __forceinline__ bool in_patch(const float* x, int r) {
  float a = x[r * 3], b = x[r * 3 + 1], c = x[r * 3 + 2];
  int c0 = min(max((int)floorf(a * 10.0f), 0), 9);
  int c1 = min(max((int)floorf(b * 10.0f), 0), 9);
  int c2 = min(max((int)floorf(c * 10.0f), 0), 9);
  return (c0 == 9) && (c1 == 9) && (c2 == 5);  // patch id 995
}
__global__ void K_count(const float* x, unsigned* counts) {
  __shared__ unsigned sw[4];
  int b = blockIdx.x, t = threadIdx.x;
  int base = b * 1024 + t * 4;
  unsigned c = 0;
#pragma unroll
  for (int j = 0; j < 4; ++j) c += in_patch(x, base + j) ? 1u : 0u;
#pragma unroll
  for (int o = 1; o < 64; o <<= 1) c += __shfl_xor((int)c, o, 64);
  if ((t & 63) == 0) sw[t >> 6] = c;
  __syncthreads();
  if (t == 0) counts[b] = sw[0] + sw[1] + sw[2] + sw[3];
}
__global__ void K_scan(const unsigned* counts, unsigned* bases) {
  __shared__ unsigned s[256];
  int t = threadIdx.x;
  unsigned c = counts[t];
  s[t] = c; __syncthreads();
  for (int o = 1; o < 256; o <<= 1) {
    unsigned v = (t >= o) ? s[t - o] : 0u;
    __syncthreads();
    s[t] += v;
    __syncthreads();
  }
  bases[t] = s[t] - c;
}
__global__ void K_fill(const float* x, const unsigned* bases, int* idx) {
  __shared__ unsigned s[256];
  int b = blockIdx.x, t = threadIdx.x;
  int base = b * 1024 + t * 4;
  unsigned fm = 0, c = 0;
#pragma unroll
  for (int j = 0; j < 4; ++j) {
    bool f = in_patch(x, base + j);
    fm |= (f ? 1u : 0u) << j;
    c += f ? 1u : 0u;
  }
  s[t] = c; __syncthreads();
  for (int o = 1; o < 256; o <<= 1) {
    unsigned v = (t >= o) ? s[t - o] : 0u;
    __syncthreads();
    s[t] += v;
    __syncthreads();
  }
  unsigned pos = bases[b] + s[t] - c;
#pragma unroll
  for (int j = 0; j < 4; ++j)
    if (fm & (1u << j)) idx[pos++] = base + j;
}

// ------------------ finalize params + broadcast part of o-layer1 ------------------
__global__ void K_vec(const unsigned* gkeys, const float* ow0, const float* ob0, float* vec0) {
  __shared__ float gp[256], lp[256];
  int t = threadIdx.x;
  gp[t] = unfkey(gkeys[t]);        // tb -> global_param
  lp[t] = unfkey(gkeys[256 + t]);  // br -> local_param
  __syncthreads();
  float acc = ob0[t];
  for (int k = 0; k < 256; ++k) {
    acc = fmaf(lp[k], ow0[(256 + k) * 256 + t], acc);
    acc = fmaf(gp[k], ow0[(512 + k) * 256 + t], acc);
  }
  vec0[t] = acc;
}

// ------------------ patch pipeline: tr-MLP + out-MLP + gt copy ------------------
struct SmallArgs {
  const float* x; const float* y; const int* idx; int MM;
  const __bf16* wt;
  const float* trb0; const float* trb1; const float* trb2; const float* trb3;
  const float* vec0; const float* ob1; const float* ow2; const float* ob2;
  float* out;
};
__global__ __launch_bounds__(256, 2) void K_small(SmallArgs a) {
  __shared__ char lds[73728];
  int tid = threadIdx.x, lane = tid & 63, wave = tid >> 6;
  int pr0 = blockIdx.x << 7;
  const __bf16* wt6 = a.wt + (size_t)6 * WT_SLOT;
  const __bf16* w0f = a.wt + (size_t)11 * WT_SLOT + 2 * 8192;  // tr mini
  char* mini = lds + 65536;
  {  // gather x_patch -> mini tile
    for (int s = tid; s < 512; s += 256) {
      int r = s & 127, ch = s >> 7;
      bf16x8 v;
#pragma unroll
      for (int j = 0; j < 8; ++j) v[j] = (__bf16)0.f;
      if (ch == 0) {
        int j = a.idx[min(pr0 + r, a.MM - 1)];
        v[0] = (__bf16)a.x[j * 3]; v[1] = (__bf16)a.x[j * 3 + 1]; v[2] = (__bf16)a.x[j * 3 + 2];
      }
      *(bf16x8*)(mini + r * 64 + ch * 16) = v;
    }
  }
  if (tid < 128 && pr0 + tid < a.MM) a.out[a.MM + pr0 + tid] = a.y[a.idx[pr0 + tid]];
  bf16x8 b0f[4];
#pragma unroll
  for (int i = 0; i < 4; ++i) b0f[i] = *(const bf16x8*)(w0f + (wave * 4 + i) * 512 + lane * 8);
  bf16x8 br0[8], br1[8];
  load_bpair(wt6, wave, lane, 0, br0);
  __syncthreads();
  layer0_mfma<true>(lds, mini, b0f, a.trb0, lane, wave);
  layer256<true, true, false>(lds, wt6, wt6 + WT_SLOT, a.trb1, lane, wave, nullptr, br0, br1);
  layer256<true, true, false>(lds, wt6 + WT_SLOT, wt6 + 2 * WT_SLOT, a.trb2, lane, wave, nullptr, br0, br1);
  layer256<false, true, false>(lds, wt6 + 2 * WT_SLOT, a.wt + (size_t)9 * WT_SLOT, a.trb3, lane, wave, nullptr, br0, br1);  // local_coord
  layer256<true, true, false>(lds, a.wt + (size_t)9 * WT_SLOT, a.wt + (size_t)10 * WT_SLOT, a.vec0, lane, wave, nullptr, br0, br1);  // o1
  layer256<true, true, false>(lds, a.wt + (size_t)10 * WT_SLOT, a.wt + (size_t)10 * WT_SLOT, a.ob1, lane, wave, nullptr, br0, br1);  // o2
  {  // o3: 256 -> 1 dot per row, fp32 out
    int r = tid >> 1, half = tid & 1, pr = pr0 + r;
    float s = 0.f;
    for (int i = 0; i < 128; ++i) {
      int c = (half << 7) + i;
      s = fmaf((float)*(const __bf16*)(lds + lds_off(r, 2 * c)), a.ow2[c], s);
    }
    s += __shfl_xor(s, 1, 64);
    if (half == 0 && pr < a.MM) a.out[pr] = s + a.ob2[0];
  }
}

extern "C" void kernel_launch(void* const* d_in, const int* in_sizes, int n_in,
                              void* d_out, int out_size, void* d_ws, size_t ws_size,
                              hipStream_t stream) {
  const float* x = (const float*)d_in[0];
  const float* y = (const float*)d_in[1];
  char* ws = (char*)d_ws;
  unsigned* gkeys = (unsigned*)(ws + WS_GKEYS);
  float* vec0 = (float*)(ws + WS_VEC0);
  unsigned* counts = (unsigned*)(ws + WS_COUNTS);
  unsigned* bases = (unsigned*)(ws + WS_BASES);
  int* idx = (int*)(ws + WS_IDX);
  __bf16* wt = (__bf16*)(ws + WS_WT);
  int MM = out_size / 2;

  ConvArgs ca;
  for (int m = 0; m < 3; ++m)           // 0=tb,1=br,2=tr ; L -> w_{L+1}
    for (int L = 0; L < 3; ++L)
      ca.src[m * 3 + L] = (const float*)d_in[2 + m * 8 + 2 * (L + 1)];
  ca.src[9] = (const float*)d_in[26];   // o_w0 (top 256 rows used)
  ca.src[10] = (const float*)d_in[28];  // o_w1
  ca.src[11] = (const float*)d_in[2];   // tb_w0 (3x256)
  ca.src[12] = (const float*)d_in[10];  // br_w0
  ca.src[13] = (const float*)d_in[18];  // tr_w0
  hipLaunchKernelGGL(K_conv, dim3(15, 16), dim3(256), 0, stream, ca, wt, gkeys);

  K_count<<<256, 256, 0, stream>>>(x, counts);
  K_scan<<<1, 256, 0, stream>>>(counts, bases);
  K_fill<<<256, 256, 0, stream>>>(x, bases, idx);

  BigArgs ba;
  ba.x = x; ba.wt = wt; ba.gkeys = gkeys;
  ba.b0[0] = (const float*)d_in[3];  ba.b1[0] = (const float*)d_in[5];
  ba.b2[0] = (const float*)d_in[7];  ba.b3[0] = (const float*)d_in[9];
  ba.b0[1] = (const float*)d_in[11]; ba.b1[1] = (const float*)d_in[13];
  ba.b2[1] = (const float*)d_in[15]; ba.b3[1] = (const float*)d_in[17];
  K_big<<<4096, 256, 0, stream>>>(ba);

  K_vec<<<1, 256, 0, stream>>>(gkeys, (const float*)d_in[26], (const float*)d_in[27], vec0);

  if (MM > 0) {
    SmallArgs sa;
    sa.x = x; sa.y = y; sa.idx = idx; sa.MM = MM; sa.wt = wt;
    sa.trb0 = (const float*)d_in[19]; sa.trb1 = (const float*)d_in[21];
    sa.trb2 = (const float*)d_in[23]; sa.trb3 = (const float*)d_in[25];
    sa.vec0 = vec0;
    sa.ob1 = (const float*)d_in[29];
    sa.ow2 = (const float*)d_in[30]; sa.ob2 = (const float*)d_in[31];
    sa.out = (float*)d_out;
    K_small<<<(MM + 127) / 128, 256, 0, stream>>>(sa);
  }
}

// Round 8
// 254.696 us; speedup vs baseline: 4.6871x; 1.0947x over previous
//
#include <hip/hip_runtime.h>

typedef __bf16 bf16x8 __attribute__((ext_vector_type(8)));
typedef float f32x4 __attribute__((ext_vector_type(4)));

#define WT_SLOT 65536              // elements per 256x256 bf16 weight slot (packed fragment order)
#define WS_GKEYS 0                 // 512 u32 (tb keys, br keys)
#define WS_VEC0  4096              // 256 f32
#define WS_COUNTS 8192             // 256 u32
#define WS_BASES 12288             // 256 u32
#define WS_IDX   16384             // 4096 i32
#define WS_WT    32768             // 12 slots * 131072 B (slot 11 = 3 packed-W0 minis)

#define TANH_K 2.8853900817779268f   // 2*log2(e); tanh layers have W,b pre-scaled by this

__device__ __forceinline__ unsigned fkey(float f) {
  unsigned u = __float_as_uint(f);
  return (u & 0x80000000u) ? ~u : (u | 0x80000000u);
}
__device__ __forceinline__ float unfkey(unsigned k) {
  unsigned u = (k & 0x80000000u) ? (k & 0x7FFFFFFFu) : ~k;
  return __uint_as_float(u);
}
// swizzled LDS byte offset for a [128][256] bf16 tile, row stride 512B
__device__ __forceinline__ int lds_off(int r, int cb) {
  return r * 512 + (cb ^ ((r & 7) << 4));
}
// tanh from pre-scaled input t = 2log2e*x : 1 - 2/(exp2(t)+1)
__device__ __forceinline__ float tanh_scaled(float t) {
  float e = __builtin_amdgcn_exp2f(t);
  return fmaf(__builtin_amdgcn_rcpf(e + 1.0f), -2.0f, 1.0f);
}
// T12-verified packed bf16 convert (2 f32 -> 1 u32)
__device__ __forceinline__ unsigned cvt_pk_bf16(float lo, float hi) {
  unsigned d;
  asm("v_cvt_pk_bf16_f32 %0, %1, %2" : "=v"(d) : "v"(lo), "v"(hi));
  return d;
}

// Packed B layout: element (n = nt*16 + (l&15), k = ks*32 + (l>>4)*8 + j) at
// linear ks*8192 + nt*512 + l*8 + j. Wave w owns nt = 4w..4w+3 (cols 64w..64w+63).
__device__ __forceinline__ void load_bpair(const __bf16* wt, int wave, int lane, int p,
                                           bf16x8 b[8]) {
  const __bf16* base = wt + p * 16384 + wave * 2048 + lane * 8;
#pragma unroll
  for (int h = 0; h < 2; ++h)
#pragma unroll
    for (int i = 0; i < 4; ++i)
      b[h * 4 + i] = *(const bf16x8*)(base + h * 8192 + i * 512);
}

// Swapped-operand MFMA: mfma(W_frag, A_frag, acc) -> lane holds rows rt*16+(lane&15),
// cols cbase + (lane>>4)*4 + rg (4 consecutive).
__device__ __forceinline__ void compute_pair(char* lds, const bf16x8 bc[8], int ksbase,
                                             int rlo, int khi2, f32x4 acc[8][4]) {
#pragma unroll
  for (int h = 0; h < 2; ++h) {
    int cb = (ksbase + h) * 64 + khi2;   // byte column of this k-chunk
#pragma unroll
    for (int rt = 0; rt < 8; ++rt) {
      bf16x8 av = *(const bf16x8*)(lds + lds_off(rt * 16 + rlo, cb));
#pragma unroll
      for (int i = 0; i < 4; ++i)
        acc[rt][i] = __builtin_amdgcn_mfma_f32_16x16x32_bf16(bc[h * 4 + i], av, acc[rt][i], 0, 0, 0);
    }
  }
}

// bias is already inside acc (C-operand init); epilogue = activation + pack + store.
template <bool TANH, bool WRITE, bool CMAX>
__device__ __forceinline__ void epilogue(char* lds, int lane, int wave,
                                         f32x4 acc[8][4], float* mbuf) {
  const int rlo = lane & 15;
  const int q4 = (lane >> 4) << 2;
#pragma unroll
  for (int i = 0; i < 4; ++i) {
    const int cbase = (wave * 4 + i) * 16 + q4;       // 4 consecutive cols per lane
    f32x4 cm;
#pragma unroll
    for (int rt = 0; rt < 8; ++rt) {
      f32x4 v;
#pragma unroll
      for (int rg = 0; rg < 4; ++rg) {
        float t = acc[rt][i][rg];
        if (TANH) t = tanh_scaled(t);
        v[rg] = t;
      }
      if (WRITE) {
        uint2 pv;
        pv.x = cvt_pk_bf16(v[0], v[1]);
        pv.y = cvt_pk_bf16(v[2], v[3]);
        *(uint2*)(lds + lds_off(rt * 16 + rlo, 2 * cbase)) = pv;
      }
      if (CMAX) {
        if (rt == 0) cm = v;
        else {
#pragma unroll
          for (int rg = 0; rg < 4; ++rg) cm[rg] = fmaxf(cm[rg], v[rg]);
        }
      }
    }
    if (CMAX) {  // reduce over rows (lane&15 across lanes), cols distinct per (q,rg)
#pragma unroll
      for (int rg = 0; rg < 4; ++rg) {
#pragma unroll
        for (int off = 1; off <= 8; off <<= 1)
          cm[rg] = fmaxf(cm[rg], __shfl_xor(cm[rg], off, 64));
      }
      if (rlo == 0) *(f32x4*)(mbuf + cbase) = cm;
    }
  }
}

// acc init = bias (x TANH_K for tanh layers, whose W is pre-scaled likewise)
template <bool TANH>
__device__ __forceinline__ void acc_init(f32x4 acc[8][4], const float* bias, int lane, int wave) {
  const int q4 = (lane >> 4) << 2;
#pragma unroll
  for (int i = 0; i < 4; ++i) {
    f32x4 bv = *(const f32x4*)(bias + (wave * 4 + i) * 16 + q4);
    if (TANH) {
#pragma unroll
      for (int rg = 0; rg < 4; ++rg) bv[rg] *= TANH_K;
    }
#pragma unroll
    for (int rt = 0; rt < 8; ++rt) acc[rt][i] = bv;
  }
}

// One 256->256 layer. Precondition: b0 holds THIS layer's pair0. Post: b0 holds wt_next pair0.
template <bool TANH, bool WRITE, bool CMAX>
__device__ __forceinline__ void layer256(char* lds, const __bf16* wt, const __bf16* wt_next,
                                         const float* bias, int lane, int wave, float* mbuf,
                                         bf16x8 b0[8], bf16x8 b1[8]) {
  const int rlo = lane & 15;
  const int khi2 = (lane >> 4) << 4;   // byte offset of k-subrange
  f32x4 acc[8][4];
  acc_init<TANH>(acc, bias, lane, wave);

  load_bpair(wt, wave, lane, 1, b1);
  compute_pair(lds, b0, 0, rlo, khi2, acc);
  load_bpair(wt, wave, lane, 2, b0);
  compute_pair(lds, b1, 2, rlo, khi2, acc);
  load_bpair(wt, wave, lane, 3, b1);
  compute_pair(lds, b0, 4, rlo, khi2, acc);
  load_bpair(wt_next, wave, lane, 0, b0);   // prefetch next layer's pair0
  compute_pair(lds, b1, 6, rlo, khi2, acc);

  __syncthreads();                          // all act-tile reads done before overwrite
  epilogue<TANH, WRITE, CMAX>(lds, lane, wave, acc, mbuf);
  __syncthreads();
}

// layer0 (K=32) via MFMA on the mini x-tile; b0f = 4 packed (pre-scaled) W0 fragments
__device__ __forceinline__ void layer0_mfma(char* lds, const char* mini, const bf16x8 b0f[4],
                                            const float* bias, int lane, int wave) {
  const int rlo = lane & 15;
  const int khi2 = (lane >> 4) << 4;
  f32x4 acc[8][4];
  acc_init<true>(acc, bias, lane, wave);
#pragma unroll
  for (int rt = 0; rt < 8; ++rt) {
    bf16x8 av = *(const bf16x8*)(mini + (rt * 16 + rlo) * 64 + khi2);
#pragma unroll
    for (int i = 0; i < 4; ++i)
      acc[rt][i] = __builtin_amdgcn_mfma_f32_16x16x32_bf16(b0f[i], av, acc[rt][i], 0, 0, 0);
  }
  epilogue<true, true, false>(lds, lane, wave, acc, nullptr);
  __syncthreads();
}

// ------------------ weight convert/transpose/pack to bf16 (tanh layers pre-scaled) ------------------
struct ConvArgs { const float* src[14]; };
__global__ void K_conv(ConvArgs a, __bf16* wt, unsigned* gkeys) {
  int job = blockIdx.x, t = threadIdx.x, y = blockIdx.y;
  if (job == 14) {
    if (y == 0) { gkeys[t] = 0u; gkeys[256 + t] = 0u; }
    return;
  }
  if (job >= 11) {  // W0 minis: (3,256) fp32 -> one K=32 fragment chunk, zero-padded, tanh-scaled
    if (y >= 2) return;
    const float* s = a.src[job];
    __bf16* d = wt + (size_t)11 * WT_SLOT + (job - 11) * 8192;
#pragma unroll
    for (int it = 0; it < 16; ++it) {
      int p = y * 4096 + it * 256 + t;
      int nt = (p >> 9) & 15, ln = (p >> 3) & 63, j = p & 7;
      int n = nt * 16 + (ln & 15);
      int k = ((ln >> 4) << 3) + j;
      d[p] = (k < 3) ? (__bf16)(TANH_K * s[k * 256 + n]) : (__bf16)0.f;
    }
    return;
  }
  // jobs 0..10: tanh layers (all except job%3==2 within 0..8) scaled by TANH_K
  const float scale = (job >= 9 || (job % 3) != 2) ? TANH_K : 1.0f;
  const float* s = a.src[job];
  __bf16* d = wt + (size_t)job * WT_SLOT;
#pragma unroll
  for (int it = 0; it < 16; ++it) {
    int p = y * 4096 + it * 256 + t;                 // packed linear index
    int ks = p >> 13, nt = (p >> 9) & 15, ln = (p >> 3) & 63, j = p & 7;
    int n = nt * 16 + (ln & 15);
    int k = ks * 32 + ((ln >> 4) << 3) + j;
    d[p] = (__bf16)(scale * s[(k << 8) | n]);        // src is [K][N] fp32 (first 256 rows)
  }
}

// ------------------ big fused MLP (tb & br) + column max ------------------
struct BigArgs {
  const float* x;
  const __bf16* wt;
  const float* b0[2]; const float* b1[2]; const float* b2[2]; const float* b3[2];
  unsigned* gkeys;
};
__global__ __launch_bounds__(256, 2) void K_big(BigArgs a) {
  __shared__ char lds[73728];          // 64KB act tile + 8KB mini x-tile
  int tid = threadIdx.x, lane = tid & 63, wave = tid >> 6;
  int mlp = blockIdx.x >> 11;
  int row0 = (blockIdx.x & 2047) << 7;
  const __bf16* wt = a.wt + (size_t)(mlp * 3) * WT_SLOT;
  const __bf16* w0f = a.wt + (size_t)11 * WT_SLOT + mlp * 8192;
  char* mini = lds + 65536;
  {  // stage x -> bf16 mini tile [128][32] (k=0..2 data, rest zeros)
    const float* xr = a.x + (size_t)row0 * 3;
    for (int s = tid; s < 512; s += 256) {
      int r = s & 127, ch = s >> 7;
      bf16x8 v;
#pragma unroll
      for (int j = 0; j < 8; ++j) v[j] = (__bf16)0.f;
      if (ch == 0) {
        v[0] = (__bf16)xr[r * 3]; v[1] = (__bf16)xr[r * 3 + 1]; v[2] = (__bf16)xr[r * 3 + 2];
      }
      *(bf16x8*)(mini + r * 64 + ch * 16) = v;
    }
  }
  bf16x8 b0f[4];
#pragma unroll
  for (int i = 0; i < 4; ++i) b0f[i] = *(const bf16x8*)(w0f + (wave * 4 + i) * 512 + lane * 8);
  bf16x8 br0[8], br1[8];
  load_bpair(wt, wave, lane, 0, br0);   // prefetch layer-1 pair0
  __syncthreads();
  layer0_mfma(lds, mini, b0f, a.b0[mlp], lane, wave);
  float* mbuf = (float*)mini;           // mini region free after layer0
  layer256<true, true, false>(lds, wt, wt + WT_SLOT, a.b1[mlp], lane, wave, nullptr, br0, br1);
  layer256<true, true, false>(lds, wt + WT_SLOT, wt + 2 * WT_SLOT, a.b2[mlp], lane, wave, nullptr, br0, br1);
  layer256<false, false, true>(lds, wt + 2 * WT_SLOT, wt + 2 * WT_SLOT, a.b3[mlp], lane, wave, mbuf, br0, br1);
  // per-column block max -> one atomic per column (max = commutative -> deterministic)
  atomicMax(a.gkeys + mlp * 256 + tid, fkey(mbuf[tid]));
}

// ------------------ patch membership / ordered compaction ------------------
__device__ __forceinline__ bool in_patch(const float* x, int r) {
  float a = x[r * 3], b = x[r * 3 + 1], c = x[r * 3 + 2];
  int c0 = min(max((int)floorf(a * 10.0f), 0), 9);
  int c1 = min(max((int)floorf(b * 10.0f), 0), 9);
  int c2 = min(max((int)floorf(c * 10.0f), 0), 9);
  return (c0 == 9) && (c1 == 9) && (c2 == 5);  // patch id 995
}
__global__ void K_count(const float* x, unsigned* counts) {
  __shared__ unsigned sw[4];
  int b = blockIdx.x, t = threadIdx.x;
  int base = b * 1024 + t * 4;
  unsigned c = 0;
#pragma unroll
  for (int j = 0; j < 4; ++j) c += in_patch(x, base + j) ? 1u : 0u;
#pragma unroll
  for (int o = 1; o < 64; o <<= 1) c += __shfl_xor((int)c, o, 64);
  if ((t & 63) == 0) sw[t >> 6] = c;
  __syncthreads();
  if (t == 0) counts[b] = sw[0] + sw[1] + sw[2] + sw[3];
}
__global__ void K_scan(const unsigned* counts, unsigned* bases) {
  __shared__ unsigned s[256];
  int t = threadIdx.x;
  unsigned c = counts[t];
  s[t] = c; __syncthreads();
  for (int o = 1; o < 256; o <<= 1) {
    unsigned v = (t >= o) ? s[t - o] : 0u;
    __syncthreads();
    s[t] += v;
    __syncthreads();
  }
  bases[t] = s[t] - c;
}
__global__ void K_fill(const float* x, const unsigned* bases, int* idx) {
  __shared__ unsigned s[256];
  int b = blockIdx.x, t = threadIdx.x;
  int base = b * 1024 + t * 4;
  unsigned fm = 0, c = 0;
#pragma unroll
  for (int j = 0; j < 4; ++j) {
    bool f = in_patch(x, base + j);
    fm |= (f ? 1u : 0u) << j;
    c += f ? 1u : 0u;
  }
  s[t] = c; __syncthreads();
  for (int o = 1; o < 256; o <<= 1) {
    unsigned v = (t >= o) ? s[t - o] : 0u;
    __syncthreads();
    s[t] += v;
    __syncthreads();
  }
  unsigned pos = bases[b] + s[t] - c;
#pragma unroll
  for (int j = 0; j < 4; ++j)
    if (fm & (1u << j)) idx[pos++] = base + j;
}

// ------------------ finalize params + broadcast part of o-layer1 (unscaled) ------------------
__global__ void K_vec(const unsigned* gkeys, const float* ow0, const float* ob0, float* vec0) {
  __shared__ float gp[256], lp[256];
  int t = threadIdx.x;
  gp[t] = unfkey(gkeys[t]);        // tb -> global_param
  lp[t] = unfkey(gkeys[256 + t]);  // br -> local_param
  __syncthreads();
  float acc = ob0[t];
  for (int k = 0; k < 256; ++k) {
    acc = fmaf(lp[k], ow0[(256 + k) * 256 + t], acc);
    acc = fmaf(gp[k], ow0[(512 + k) * 256 + t], acc);
  }
  vec0[t] = acc;
}

// ------------------ patch pipeline: tr-MLP + out-MLP + gt copy ------------------
struct SmallArgs {
  const float* x; const float* y; const int* idx; int MM;
  const __bf16* wt;
  const float* trb0; const float* trb1; const float* trb2; const float* trb3;
  const float* vec0; const float* ob1; const float* ow2; const float* ob2;
  float* out;
};
__global__ __launch_bounds__(256, 2) void K_small(SmallArgs a) {
  __shared__ char lds[73728];
  int tid = threadIdx.x, lane = tid & 63, wave = tid >> 6;
  int pr0 = blockIdx.x << 7;
  const __bf16* wt6 = a.wt + (size_t)6 * WT_SLOT;
  const __bf16* w0f = a.wt + (size_t)11 * WT_SLOT + 2 * 8192;  // tr mini
  char* mini = lds + 65536;
  {  // gather x_patch -> mini tile
    for (int s = tid; s < 512; s += 256) {
      int r = s & 127, ch = s >> 7;
      bf16x8 v;
#pragma unroll
      for (int j = 0; j < 8; ++j) v[j] = (__bf16)0.f;
      if (ch == 0) {
        int j = a.idx[min(pr0 + r, a.MM - 1)];
        v[0] = (__bf16)a.x[j * 3]; v[1] = (__bf16)a.x[j * 3 + 1]; v[2] = (__bf16)a.x[j * 3 + 2];
      }
      *(bf16x8*)(mini + r * 64 + ch * 16) = v;
    }
  }
  if (tid < 128 && pr0 + tid < a.MM) a.out[a.MM + pr0 + tid] = a.y[a.idx[pr0 + tid]];
  bf16x8 b0f[4];
#pragma unroll
  for (int i = 0; i < 4; ++i) b0f[i] = *(const bf16x8*)(w0f + (wave * 4 + i) * 512 + lane * 8);
  bf16x8 br0[8], br1[8];
  load_bpair(wt6, wave, lane, 0, br0);
  __syncthreads();
  layer0_mfma(lds, mini, b0f, a.trb0, lane, wave);
  layer256<true, true, false>(lds, wt6, wt6 + WT_SLOT, a.trb1, lane, wave, nullptr, br0, br1);
  layer256<true, true, false>(lds, wt6 + WT_SLOT, wt6 + 2 * WT_SLOT, a.trb2, lane, wave, nullptr, br0, br1);
  layer256<false, true, false>(lds, wt6 + 2 * WT_SLOT, a.wt + (size_t)9 * WT_SLOT, a.trb3, lane, wave, nullptr, br0, br1);  // local_coord
  layer256<true, true, false>(lds, a.wt + (size_t)9 * WT_SLOT, a.wt + (size_t)10 * WT_SLOT, a.vec0, lane, wave, nullptr, br0, br1);  // o1
  layer256<true, true, false>(lds, a.wt + (size_t)10 * WT_SLOT, a.wt + (size_t)10 * WT_SLOT, a.ob1, lane, wave, nullptr, br0, br1);  // o2
  {  // o3: 256 -> 1 dot per row, fp32 out
    int r = tid >> 1, half = tid & 1, pr = pr0 + r;
    float s = 0.f;
    for (int i = 0; i < 128; ++i) {
      int c = (half << 7) + i;
      s = fmaf((float)*(const __bf16*)(lds + lds_off(r, 2 * c)), a.ow2[c], s);
    }
    s += __shfl_xor(s, 1, 64);
    if (half == 0 && pr < a.MM) a.out[pr] = s + a.ob2[0];
  }
}

extern "C" void kernel_launch(void* const* d_in, const int* in_sizes, int n_in,
                              void* d_out, int out_size, void* d_ws, size_t ws_size,
                              hipStream_t stream) {
  const float* x = (const float*)d_in[0];
  const float* y = (const float*)d_in[1];
  char* ws = (char*)d_ws;
  unsigned* gkeys = (unsigned*)(ws + WS_GKEYS);
  float* vec0 = (float*)(ws + WS_VEC0);
  unsigned* counts = (unsigned*)(ws + WS_COUNTS);
  unsigned* bases = (unsigned*)(ws + WS_BASES);
  int* idx = (int*)(ws + WS_IDX);
  __bf16* wt = (__bf16*)(ws + WS_WT);
  int MM = out_size / 2;

  ConvArgs ca;
  for (int m = 0; m < 3; ++m)           // 0=tb,1=br,2=tr ; L -> w_{L+1}
    for (int L = 0; L < 3; ++L)
      ca.src[m * 3 + L] = (const float*)d_in[2 + m * 8 + 2 * (L + 1)];
  ca.src[9] = (const float*)d_in[26];   // o_w0 (top 256 rows used)
  ca.src[10] = (const float*)d_in[28];  // o_w1
  ca.src[11] = (const float*)d_in[2];   // tb_w0 (3x256)
  ca.src[12] = (const float*)d_in[10];  // br_w0
  ca.src[13] = (const float*)d_in[18];  // tr_w0
  hipLaunchKernelGGL(K_conv, dim3(15, 16), dim3(256), 0, stream, ca, wt, gkeys);

  K_count<<<256, 256, 0, stream>>>(x, counts);
  K_scan<<<1, 256, 0, stream>>>(counts, bases);
  K_fill<<<256, 256, 0, stream>>>(x, bases, idx);

  BigArgs ba;
  ba.x = x; ba.wt = wt; ba.gkeys = gkeys;
  ba.b0[0] = (const float*)d_in[3];  ba.b1[0] = (const float*)d_in[5];
  ba.b2[0] = (const float*)d_in[7];  ba.b3[0] = (const float*)d_in[9];
  ba.b0[1] = (const float*)d_in[11]; ba.b1[1] = (const float*)d_in[13];
  ba.b2[1] = (const float*)d_in[15]; ba.b3[1] = (const float*)d_in[17];
  K_big<<<4096, 256, 0, stream>>>(ba);

  K_vec<<<1, 256, 0, stream>>>(gkeys, (const float*)d_in[26], (const float*)d_in[27], vec0);

  if (MM > 0) {
    SmallArgs sa;
    sa.x = x; sa.y = y; sa.idx = idx; sa.MM = MM; sa.wt = wt;
    sa.trb0 = (const float*)d_in[19]; sa.trb1 = (const float*)d_in[21];
    sa.trb2 = (const float*)d_in[23]; sa.trb3 = (const float*)d_in[25];
    sa.vec0 = vec0;
    sa.ob1 = (const float*)d_in[29];
    sa.ow2 = (const float*)d_in[30]; sa.ob2 = (const float*)d_in[31];
    sa.out = (float*)d_out;
    K_small<<<(MM + 127) / 128, 256, 0, stream>>>(sa);
  }
}